// Round 14
// baseline (287.372 us; speedup 1.0000x reference)
//
#include <hip/hip_runtime.h>
#include <hip/hip_bf16.h>
#include <math.h>

#define TT 2048
#define NE 256
#define NHEAD 16

typedef __attribute__((ext_vector_type(8))) short bf16x8;
typedef __attribute__((ext_vector_type(4))) float f32x4;
typedef __attribute__((ext_vector_type(16))) float f32x16;
typedef unsigned short ushort;
typedef __attribute__((ext_vector_type(8))) unsigned short us8;

__device__ __forceinline__ short f2bf(float x) {
  __hip_bfloat16 h = __float2bfloat16(x);
  return *reinterpret_cast<short*>(&h);
}
__device__ __forceinline__ float bf2f(ushort u) {
  unsigned v = ((unsigned)u) << 16;
  return __uint_as_float(v);
}

// ---------------- fused prep: logmap (blocks 0..4095) + TILED weight transpose ----------------
__global__ __launch_bounds__(256) void prep_kernel(
    const float* __restrict__ x, ushort* __restrict__ xhb, ushort* __restrict__ xbf,
    const float* __restrict__ W_dqn, const float* __restrict__ W_dqr,
    const float* __restrict__ W_dkn, const float* __restrict__ W_dv,
    const float* __restrict__ W_selk, const float* __restrict__ W_selv,
    const float* __restrict__ W_wink, const float* __restrict__ W_winv,
    const float* __restrict__ W_proj, const float* __restrict__ W_cq,
    const float* __restrict__ W_ckv, const float* __restrict__ W_kr,
    const float* __restrict__ W_gate, const float* __restrict__ W_imp,
    ushort* __restrict__ Wt_q, ushort* __restrict__ Wt_kv,
    ushort* __restrict__ Wt_sel, ushort* __restrict__ Wt_win,
    ushort* __restrict__ Wt_proj, ushort* __restrict__ Wt_cq,
    ushort* __restrict__ Wt_nkv, float* __restrict__ gacc) {
  __shared__ float red[16];
  __shared__ float tl[64 * 65];  // transpose tile (+1 pad)
  int bx = blockIdx.x, tid = threadIdx.x;
  if (bx < 4096) {  // ---- logmap ----
    int row = bx;
    int t = row & (TT - 1);
    float uv = x[row * NE + tid];
    float rv = (t == 0) ? 0.f : x[row * NE - NE + tid];
    xbf[row * NE + tid] = (ushort)f2bf(uv);
    float a = rv * rv, bq = uv * uv, c2 = -rv * uv;
#pragma unroll
    for (int off = 32; off > 0; off >>= 1) {
      a += __shfl_down(a, off, 64);
      bq += __shfl_down(bq, off, 64);
      c2 += __shfl_down(c2, off, 64);
    }
    if ((tid & 63) == 0) {
      int w = tid >> 6;
      red[w] = a; red[4 + w] = bq; red[8 + w] = c2;
    }
    __syncthreads();
    float xn2 = red[0] + red[1] + red[2] + red[3];
    float un2 = red[4] + red[5] + red[6] + red[7];
    float ip  = red[8] + red[9] + red[10] + red[11];
    float den = 1.f + 2.f * ip + xn2 * un2;
    float mob = ((1.f + 2.f * ip + un2) * (-rv) + (1.f - xn2) * uv) / den;
    float m2 = mob * mob;
#pragma unroll
    for (int off = 32; off > 0; off >>= 1) m2 += __shfl_down(m2, off, 64);
    if ((tid & 63) == 0) red[12 + (tid >> 6)] = m2;
    __syncthreads();
    float an2 = red[12] + red[13] + red[14] + red[15];
    float an = sqrtf(an2);
    float cf = 1.f + xn2;
    float arg = fminf(sqrtf(an), 0.999f);
    xhb[row * NE + tid] = (ushort)f2bf(cf * atanhf(arg) * mob / an);
    return;
  }
  // ---- tiled weight transpose: 368 tiles total ----
  int tix = bx - 4096;
  if (tix == 0 && tid < 6) gacc[tid] = 0.f;  // zero gate accs (before front gemm)
  int which, tn, tk, N, K;
  ushort* D;
  float scl = 1.f;
  if (tix < 48) {        // Wt_q  [1536 n][96 k], scale folded
    which = 0; tn = tix >> 1; tk = tix & 1; N = 1536; K = 96; D = Wt_q;
    scl = 0.147244458176154f;  // 1/sqrt(96)*log2(e)
  } else if (tix < 64) { // Wt_kv [1024 n][32 k]
    which = 1; tn = tix - 48; tk = 0; N = 1024; K = 32; D = Wt_kv;
  } else if (tix < 192) {  // Wt_sel [2048 n][256 k]
    which = 2; int idx = tix - 64; tn = idx >> 2; tk = idx & 3; N = 2048; K = 256; D = Wt_sel;
  } else if (tix < 320) {  // Wt_win [2048 n][256 k]
    which = 3; int idx = tix - 192; tn = idx >> 2; tk = idx & 3; N = 2048; K = 256; D = Wt_win;
  } else if (tix < 352) {  // Wt_proj [256 n][512 k]
    which = 4; int idx = tix - 320; tn = idx >> 3; tk = idx & 7; N = 256; K = 512; D = Wt_proj;
  } else if (tix < 360) {  // Wt_cq [128 n][256 k] (pad n>=96)
    which = 5; int idx = tix - 352; tn = idx >> 2; tk = idx & 3; N = 128; K = 256; D = Wt_cq;
  } else {                 // Wt_nkv [128 n][256 k]: [ckv32|kr64|gate3|imp1|pad]
    which = 6; int idx = tix - 360; tn = idx >> 2; tk = idx & 3; N = 128; K = 256; D = Wt_nkv;
  }
  int n0 = tn * 64, k0 = tk * 64;
#pragma unroll
  for (int it = 0; it < 16; ++it) {
    int flat = it * 256 + tid;
    int kk = flat >> 6, nn = flat & 63;
    int k = k0 + kk, n = n0 + nn;
    float v = 0.f;
    if (k < K) {
      if (which == 0)      v = ((n < 512) ? W_dqn[(size_t)k * 512 + n]
                                          : W_dqr[(size_t)k * 1024 + (n - 512)]) * scl;
      else if (which == 1) v = (n < 512) ? W_dkn[(size_t)k * 512 + n]
                                         : W_dv[(size_t)k * 512 + (n - 512)];
      else if (which == 2) v = (n < 1536) ? W_selk[(size_t)k * 1536 + n]
                                          : W_selv[(size_t)k * 512 + (n - 1536)];
      else if (which == 3) v = (n < 1536) ? W_wink[(size_t)k * 1536 + n]
                                          : W_winv[(size_t)k * 512 + (n - 1536)];
      else if (which == 4) v = W_proj[(size_t)k * 256 + n];
      else if (which == 5) v = (n < 96) ? W_cq[(size_t)k * 96 + n] : 0.f;
      else {
        if (n < 32)       v = W_ckv[(size_t)k * 32 + n];
        else if (n < 96)  v = W_kr[(size_t)k * 64 + (n - 32)];
        else if (n < 99)  v = W_gate[(size_t)k * 3 + (n - 96)];
        else if (n == 99) v = W_imp[k];
      }
    }
    tl[kk * 65 + nn] = v;
  }
  __syncthreads();
#pragma unroll
  for (int it = 0; it < 4; ++it) {
    int flat = it * 256 + tid;        // 1024 ushort4 slots per tile
    int nl = flat >> 4, k4 = (flat & 15) * 4;
    if (k0 + k4 < K) {
      ushort4 o;
      o.x = (ushort)f2bf(tl[(k4 + 0) * 65 + nl]);
      o.y = (ushort)f2bf(tl[(k4 + 1) * 65 + nl]);
      o.z = (ushort)f2bf(tl[(k4 + 2) * 65 + nl]);
      o.w = (ushort)f2bf(tl[(k4 + 3) * 65 + nl]);
      *(ushort4*)(D + (size_t)(n0 + nl) * K + k0 + k4) = o;
    }
  }
}

// ---------------- bf16 MFMA GEMM: D[m][n] = sum_k A[m][k] * Bt[n][k] ----------------
// 4-way z-dispatch: z selects param set {1,2,3,4}; each set clipped to its
// (xlim,ylim). Set 2 supports selidx gather. ropemode: q-rope in epilogue.
// fusenorm: norm fused into epilogue (R10).
__global__ __launch_bounds__(256) void gemm_kernel(const ushort* __restrict__ A,
                                                   const ushort* __restrict__ Bt,
                                                   void* __restrict__ Out,
                                                   const ushort* __restrict__ A2,
                                                   const ushort* __restrict__ Bt2,
                                                   void* __restrict__ Out2,
                                                   const int* __restrict__ selidx2,
                                                   const ushort* __restrict__ A3,
                                                   const ushort* __restrict__ Bt3,
                                                   void* __restrict__ Out3,
                                                   const ushort* __restrict__ A4,
                                                   const ushort* __restrict__ Bt4,
                                                   void* __restrict__ Out4,
                                                   const float* __restrict__ cosp,
                                                   const float* __restrict__ sinp,
                                                   float* __restrict__ gateacc,
                                                   const float* __restrict__ kvnw,
                                                   const float* __restrict__ qnw,
                                                   const float* __restrict__ bimp,
                                                   ushort* __restrict__ krbf_o,
                                                   float* __restrict__ scores_o,
                                                   int fusenorm,
                                                   int K, int ldo, int obf16, int ropemode,
                                                   int K2, int ldo2, int obf2, int rope2,
                                                   int xlim2, int ylim2,
                                                   int K3, int ldo3, int obf3, int rope3,
                                                   int xlim3, int ylim3,
                                                   int K4, int ldo4, int obf4, int rope4,
                                                   int xlim4, int ylim4) {
  __shared__ __align__(16) short gsm[2 * 128 * 40];  // As | Bs; reused as f32 scratch
  short* As = gsm;
  short* Bs = gsm + 128 * 40;
  const int* selidx = nullptr;
  if (blockIdx.z == 1) {
    if ((int)blockIdx.x >= xlim2 || (int)blockIdx.y >= ylim2) return;
    A = A2; Bt = Bt2; Out = Out2; selidx = selidx2;
    K = K2; ldo = ldo2; obf16 = obf2; ropemode = rope2;
  } else if (blockIdx.z == 2) {
    if ((int)blockIdx.x >= xlim3 || (int)blockIdx.y >= ylim3) return;
    A = A3; Bt = Bt3; Out = Out3;
    K = K3; ldo = ldo3; obf16 = obf3; ropemode = rope3;
  } else if (blockIdx.z == 3) {
    if ((int)blockIdx.x >= xlim4 || (int)blockIdx.y >= ylim4) return;
    A = A4; Bt = Bt4; Out = Out4;
    K = K4; ldo = ldo4; obf16 = obf4; ropemode = rope4;
  }
  int m0 = blockIdx.x * 128, n0 = blockIdx.y * 128;
  int tid = threadIdx.x;
  int wv = tid >> 6, lane = tid & 63;
  int l15 = lane & 15, quad = lane >> 4;
  int wm = wv >> 1, wn = wv & 1;

  int r = tid >> 1, seg = tid & 1;
  int arow = m0 + r;
  if (selidx) arow = ((arow >> 9) * TT) + selidx[m0 + r];
  const ushort* ga = A + (size_t)arow * K + seg * 16;
  const ushort* gb = Bt + (size_t)(n0 + r) * K + seg * 16;

  f32x4 acc[4][4];
#pragma unroll
  for (int i = 0; i < 4; ++i)
#pragma unroll
    for (int j = 0; j < 4; ++j) acc[i][j] = (f32x4){0.f, 0.f, 0.f, 0.f};

  int nk = K >> 5;
  us8 apre0 = *(const us8*)ga, apre1 = *(const us8*)(ga + 8);
  us8 bpre0 = *(const us8*)gb, bpre1 = *(const us8*)(gb + 8);
  for (int kk = 0; kk < nk; ++kk) {
    __syncthreads();
    *(us8*)(As + r * 40 + seg * 16) = apre0;
    *(us8*)(As + r * 40 + seg * 16 + 8) = apre1;
    *(us8*)(Bs + r * 40 + seg * 16) = bpre0;
    *(us8*)(Bs + r * 40 + seg * 16 + 8) = bpre1;
    __syncthreads();
    if (kk + 1 < nk) {
      apre0 = *(const us8*)(ga + (kk + 1) * 32);
      apre1 = *(const us8*)(ga + (kk + 1) * 32 + 8);
      bpre0 = *(const us8*)(gb + (kk + 1) * 32);
      bpre1 = *(const us8*)(gb + (kk + 1) * 32 + 8);
    }
    bf16x8 af[4], bf[4];
#pragma unroll
    for (int mf = 0; mf < 4; ++mf)
      af[mf] = *(const bf16x8*)(As + (wm * 64 + mf * 16 + l15) * 40 + quad * 8);
#pragma unroll
    for (int nf = 0; nf < 4; ++nf)
      bf[nf] = *(const bf16x8*)(Bs + (wn * 64 + nf * 16 + l15) * 40 + quad * 8);
#pragma unroll
    for (int mf = 0; mf < 4; ++mf)
#pragma unroll
      for (int nf = 0; nf < 4; ++nf)
        acc[mf][nf] = __builtin_amdgcn_mfma_f32_16x16x32_bf16(af[mf], bf[nf], acc[mf][nf], 0, 0, 0);
  }

  if (fusenorm) {
    // -------- fused norm epilogue (front gemm; n0==0, full rows in block) --------
    __syncthreads();  // all waves' MFMA LDS reads done; gsm reusable as f32 scratch
    float* sc = (float*)gsm;  // 5120 f32 available
    if (blockIdx.z == 0) {
      // ---- nq rmsnorm over cols 0..95 -> nqb [row][96] bf16 ----
      float ss[4][4];
#pragma unroll
      for (int mf = 0; mf < 4; ++mf)
#pragma unroll
        for (int reg = 0; reg < 4; ++reg) {
          float p = acc[mf][0][reg] * acc[mf][0][reg] + acc[mf][1][reg] * acc[mf][1][reg];
          if (wn == 0) p += acc[mf][2][reg] * acc[mf][2][reg] + acc[mf][3][reg] * acc[mf][3][reg];
#pragma unroll
          for (int off = 8; off > 0; off >>= 1) p += __shfl_xor(p, off, 64);  // reduce l15
          ss[mf][reg] = p;
        }
      if (l15 == 0) {
#pragma unroll
        for (int mf = 0; mf < 4; ++mf)
#pragma unroll
          for (int reg = 0; reg < 4; ++reg)
            sc[wn * 128 + wm * 64 + mf * 16 + quad * 4 + reg] = ss[mf][reg];
      }
      __syncthreads();
#pragma unroll
      for (int mf = 0; mf < 4; ++mf) {
#pragma unroll
        for (int nf = 0; nf < 4; ++nf) {
          if (wn == 1 && nf >= 2) continue;  // cols >= 96 are pad
          int col = wn * 64 + nf * 16 + l15;
#pragma unroll
          for (int reg = 0; reg < 4; ++reg) {
            int rl = wm * 64 + mf * 16 + quad * 4 + reg;
            float sstot = sc[rl] + sc[128 + rl];
            float sca = rsqrtf(sstot / 96.f + 1e-6f) * qnw[col];
            ((ushort*)Out)[(size_t)(m0 + rl) * 96 + col] = (ushort)f2bf(acc[mf][nf][reg] * sca);
          }
        }
      }
    } else {
      // ---- gate reduce: cols 96..98 (wn==1, nf==2, l15<3) ----
      if (wn == 1 && l15 < 3) {
        float g = 0.f;
#pragma unroll
        for (int mf = 0; mf < 4; ++mf)
#pragma unroll
          for (int reg = 0; reg < 4; ++reg) g += acc[mf][2][reg];
        atomicAdd(&gateacc[(m0 >> 11) * 3 + l15], g);
      }
      // ---- scores = col 99 + b_imp (wn==1, nf==2, l15==3) ----
      if (wn == 1 && l15 == 3) {
#pragma unroll
        for (int mf = 0; mf < 4; ++mf)
#pragma unroll
          for (int reg = 0; reg < 4; ++reg)
            scores_o[m0 + wm * 64 + mf * 16 + quad * 4 + reg] = acc[mf][2][reg] + bimp[0];
      }
      // ---- kv rmsnorm cols 0..31 (wn==0; in-wave l15 reduce) -> nkvb ----
      if (wn == 0) {
#pragma unroll
        for (int mf = 0; mf < 4; ++mf) {
          float ssr[4];
#pragma unroll
          for (int reg = 0; reg < 4; ++reg) {
            float p = acc[mf][0][reg] * acc[mf][0][reg] + acc[mf][1][reg] * acc[mf][1][reg];
#pragma unroll
            for (int off = 8; off > 0; off >>= 1) p += __shfl_xor(p, off, 64);
            ssr[reg] = p;
          }
#pragma unroll
          for (int nf = 0; nf < 2; ++nf) {
            int col = nf * 16 + l15;
#pragma unroll
            for (int reg = 0; reg < 4; ++reg) {
              int rl = wm * 64 + mf * 16 + quad * 4 + reg;
              float sca = rsqrtf(ssr[reg] / 32.f + 1e-6f) * kvnw[col];
              ((ushort*)Out)[(size_t)(m0 + rl) * 32 + col] = (ushort)f2bf(acc[mf][nf][reg] * sca);
            }
          }
        }
      }
      // ---- xi exchange: wn==1 writes cols 64..95 to sc[rl*33+dd] ----
      if (wn == 1) {
#pragma unroll
        for (int mf = 0; mf < 4; ++mf)
#pragma unroll
          for (int nf = 0; nf < 2; ++nf) {
            int dd = nf * 16 + l15;
#pragma unroll
            for (int reg = 0; reg < 4; ++reg) {
              int rl = wm * 64 + mf * 16 + quad * 4 + reg;
              sc[rl * 33 + dd] = acc[mf][nf][reg];
            }
          }
      }
      __syncthreads();
      // ---- kr rope: wn==0, nf=2,3 hold xr cols 32..63; xi from LDS -> krbf ----
      if (wn == 0) {
#pragma unroll
        for (int mf = 0; mf < 4; ++mf)
#pragma unroll
          for (int nf = 2; nf < 4; ++nf) {
            int dd = (nf - 2) * 16 + l15;
#pragma unroll
            for (int reg = 0; reg < 4; ++reg) {
              int rl = wm * 64 + mf * 16 + quad * 4 + reg;
              int grow = m0 + rl;
              int t = grow & (TT - 1);
              float c = cosp[t * 32 + dd], s = sinp[t * 32 + dd];
              float xr = acc[mf][nf][reg], xi = sc[rl * 33 + dd];
              krbf_o[(size_t)grow * 64 + dd] = (ushort)f2bf(xr * c - xi * s);
              krbf_o[(size_t)grow * 64 + dd + 32] = (ushort)f2bf(xr * s + xi * c);
            }
          }
      }
    }
    return;
  }

  if (ropemode && blockIdx.y >= 4) {
    // rope pairs: cols (c, c+32) live in frags (nf, nf+2), nf in {0,1}
#pragma unroll
    for (int mf = 0; mf < 4; ++mf) {
#pragma unroll
      for (int nf = 0; nf < 2; ++nf) {
        int dd = nf * 16 + l15;
#pragma unroll
        for (int reg = 0; reg < 4; ++reg) {
          int row = m0 + wm * 64 + mf * 16 + quad * 4 + reg;
          int t = row & (TT - 1);
          float c = cosp[t * 32 + dd], s = sinp[t * 32 + dd];
          float xr = acc[mf][nf][reg], xi = acc[mf][nf + 2][reg];
          int col = n0 + wn * 64 + nf * 16 + l15;
          size_t oi = (size_t)row * ldo + col;
          ((ushort*)Out)[oi] = (ushort)f2bf(xr * c - xi * s);
          ((ushort*)Out)[oi + 32] = (ushort)f2bf(xr * s + xi * c);
        }
      }
    }
    return;
  }
#pragma unroll
  for (int mf = 0; mf < 4; ++mf) {
#pragma unroll
    for (int nf = 0; nf < 4; ++nf) {
#pragma unroll
      for (int reg = 0; reg < 4; ++reg) {
        int row = m0 + wm * 64 + mf * 16 + quad * 4 + reg;
        int col = n0 + wn * 64 + nf * 16 + l15;
        size_t oi = (size_t)row * ldo + col;
        float v = acc[mf][nf][reg];
        if (obf16) ((ushort*)Out)[oi] = (ushort)f2bf(v);
        else ((float*)Out)[oi] = v;
      }
    }
  }
}

// ---------------- top-k stage 1: ranks -> flags (32 elems x 32 subs / block) ----------------
__global__ __launch_bounds__(1024) void topk_rank_kernel(const float* __restrict__ scores,
                                                         int* __restrict__ flags) {
  int b = blockIdx.y, blk = blockIdx.x;  // blk in 0..63
  int tid = threadIdx.x;
  __shared__ unsigned sk[TT];
#pragma unroll
  for (int e = 0; e < 2; ++e) {
    int i = tid + e * 1024;
    float s = scores[b * TT + i];
    unsigned u = __float_as_uint(s);
    u = (u & 0x80000000u) ? ~u : (u | 0x80000000u);
    sk[i] = u;
  }
  __syncthreads();
  int e = blk * 32 + (tid >> 5);
  int sub = tid & 31;
  unsigned u = sk[e];
  int r = 0;
  int j0 = sub * 64;
#pragma unroll 8
  for (int j = j0; j < j0 + 64; ++j) {
    unsigned v = sk[j];
    r += (int)((v > u) || (v == u && j < e));
  }
#pragma unroll
  for (int off = 16; off > 0; off >>= 1) r += __shfl_down(r, off, 32);
  if (sub == 0) flags[b * TT + e] = (r < 512) ? 1 : 0;
}

// ---------------- top-k stage 2: wave-shfl scan + scatter (2 barriers) ----------------
__global__ __launch_bounds__(1024) void topk_scan_kernel(const int* __restrict__ flags,
                                                         int* __restrict__ selidx) {
  int b = blockIdx.x, tid = threadIdx.x;
  __shared__ int wsum[16];
  int2 f = *(const int2*)(flags + b * TT + 2 * tid);  // elements 2*tid, 2*tid+1
  int local = f.x + f.y;
  int lane = tid & 63, wv = tid >> 6;
  int sc = local;  // inclusive wave scan
#pragma unroll
  for (int off = 1; off < 64; off <<= 1) {
    int t = __shfl_up(sc, off, 64);
    if (lane >= off) sc += t;
  }
  if (lane == 63) wsum[wv] = sc;
  __syncthreads();
  int woff = 0;
  for (int w = 0; w < wv; ++w) woff += wsum[w];  // broadcast LDS reads
  int p0 = woff + (sc - local) + f.x;  // inclusive prefix at element 2*tid
  int p1 = p0 + f.y;
  if (f.x) selidx[b * 512 + p0 - 1] = 2 * tid;
  if (f.y) selidx[b * 512 + p1 - 1] = 2 * tid + 1;
}

// ---------------- fused flash attention, 32x32x16 MFMA, S^T formulation ----------------
// Phase-locked schedule (R2/R6): 512 blocks, streams cmp->sel->win SEQUENTIAL.
// 512 threads = 8 waves = 4 q-subtiles x 2 TILE-PARITIES; Q + oacc in LDS.
// __launch_bounds__(512, 2): R13's (512,4) budgeted 64 regs for a 4-blocks/CU
// case that LDS (80384 B -> 2 blocks/CU) can never reach -> forced ~1 MB spill
// + pressure-serialized scheduling. (512,2) budgets 128; live state with Q and
// oacc in LDS is ~95-100 -> no spill, same 2-blocks/CU residency.
__global__ __launch_bounds__(512, 2) void flash_fused_kernel(
    const ushort* __restrict__ qbf,    // [row][qn 512 | qr 1024] bf16, scale*log2e folded
    const ushort* __restrict__ kv,     // [row][kn 512 | v 512] bf16
    const ushort* __restrict__ krbf,   // [row][64] bf16 (roped)
    const ushort* __restrict__ selt,   // [selrow][sk 1536 | sv 512] bf16
    const ushort* __restrict__ wint,   // [row][wk 1536 | wv 512] bf16
    const float* __restrict__ gacc,    // [2][3] gate sums (from front gemm)
    const float* __restrict__ b_gate,
    ushort* __restrict__ attout) {     // [b*TT+t][h*32+d] bf16
  // shorts: Qsm 13312 | Ksm 13312 | Vtm 4608 | Ls 256 | Oacc 8704  = 40192 (80384 B)
  __shared__ __align__(16) short smem[13312 + 13312 + 4608 + 256 + 8704];
  short* Qsm = smem;                    // [128][104]
  short* Ksm = smem + 13312;            // [2][64*104]
  short* Vtm = smem + 26624;            // [2][32*72]
  float* Ls  = (float*)(smem + 31232);  // [4][32]
  float* Oac = (float*)(smem + 31488);  // [256][17] f32 (stride 17: conflict-free)

  int bx = blockIdx.x;
  int j = bx >> 5;  // 0..15
  int qtile = (j < 8) ? (15 - 2 * j) : (2 * (j - 8));
  int bh = bx & 31;
  int b = bh >> 4, h = bh & 15;
  int tid = threadIdx.x;
  int wv = tid >> 6;          // 0..7
  int qsub = wv >> 1;         // 0..3: q rows qsub*32..+31
  int khalf = wv & 1;         // tile parity
  int lane = tid & 63;
  int l31 = lane & 31, half = lane >> 5;
  int obase = (qsub * 64 + lane) * 17;  // this thread's Oac slot (khalf==0 only)

  // ---- gate softmax (uniform; 3 exp per thread) ----
  float w0, w1, w2;
  {
    float g0 = gacc[b * 3 + 0] * (1.0f / 2048.0f) + b_gate[0];
    float g1 = gacc[b * 3 + 1] * (1.0f / 2048.0f) + b_gate[1];
    float g2 = gacc[b * 3 + 2] * (1.0f / 2048.0f) + b_gate[2];
    float mx = fmaxf(g0, fmaxf(g1, g2));
    float e0 = expf(g0 - mx), e1 = expf(g1 - mx), e2 = expf(g2 - mx);
    float inv = 1.f / (e0 + e1 + e2);
    w0 = e0 * inv; w1 = e1 * inv; w2 = e2 * inv;
  }

  // ---- init Oac (self-owned slots, no barrier needed) ----
  if (khalf == 0) {
#pragma unroll
    for (int r2 = 0; r2 < 16; ++r2) Oac[obase + r2] = 0.f;
  }

  // ---- stage Q into dedicated Qsm (persistent; fragment re-read per tile) ----
  int qrow0 = qtile * 128;
  for (int i = tid; i < 128 * 24; i += 512) {
    int qi = i / 24, dp = (i - qi * 24) * 4;
    int col = (dp < 32) ? (h * 32 + dp) : (512 + h * 64 + (dp - 32));
    *(ushort4*)(Qsm + qi * 104 + dp) =
        *(const ushort4*)(qbf + (size_t)(b * TT + qrow0 + qi) * 1536 + col);
  }
  // K-loop's first __syncthreads orders Qsm staging before first reads

  short* kdst[3];
#pragma unroll
  for (int c = 0; c < 3; ++c) {
    int i = c * 512 + tid;
    int kj = i / 24, dp = (i - kj * 24) * 4;
    kdst[c] = &Ksm[kj * 104 + dp];
  }
  int vd0 = (tid & 15) * 2, vkjp = (tid >> 4) * 2;
  short* vdsta = &Vtm[(vd0 + 0) * 72 + vkjp];
  short* vdstb = &Vtm[(vd0 + 1) * 72 + vkjp];

#define PREFETCH(KP, VA, VB)                                  \
  {                                                           \
    _Pragma("unroll") for (int c = 0; c < 3; ++c) {           \
      KP[c] = *(const ushort4*)ksrc[c];                       \
      ksrc[c] += kstep[c];                                    \
    }                                                         \
    VA = *(const ushort2*)vsrcA;                              \
    VB = *(const ushort2*)vsrcB;                              \
    vsrcA += vstep;                                           \
    vsrcB += vstep;                                           \
  }

#define COMMIT(KP, VA, VB, SL)                                           \
  {                                                                      \
    _Pragma("unroll") for (int c = 0; c < 3; ++c)                        \
      *(ushort4*)(kdst[c] + (SL) * (64 * 104)) = KP[c];                  \
    *(unsigned*)(vdsta + (SL) * (32 * 72)) =                             \
        (unsigned)VA.x | ((unsigned)VB.x << 16);                         \
    *(unsigned*)(vdstb + (SL) * (32 * 72)) =                             \
        (unsigned)VA.y | ((unsigned)VB.y << 16);                         \
  }

  for (int s = 0; s < 3; ++s) {
    const ushort *kb1, *kb2, *vb;
    size_t krs1, krs2, vrs;
    int split, Tk, causal;
    if (s == 0) {  // cmp
      kb1 = kv + h * 32;        krs1 = 1024; split = 32;
      kb2 = krbf;               krs2 = 64;
      vb = kv + 512 + h * 32;   vrs = 1024;
      Tk = TT; causal = 1;
    } else if (s == 1) {  // sel
      kb1 = selt + h * 96;      krs1 = 2048; split = 96;
      kb2 = selt;               krs2 = 2048;
      vb = selt + 1536 + h * 32; vrs = 2048;
      Tk = 512; causal = 0;
    } else {  // win
      kb1 = wint + h * 96;      krs1 = 2048; split = 96;
      kb2 = wint;               krs2 = 2048;
      vb = wint + 1536 + h * 32; vrs = 2048;
      Tk = TT; causal = 1;
    }
    size_t bTk = (size_t)b * Tk;

    const ushort* ksrc[3];
    int kstep[3];
#pragma unroll
    for (int c = 0; c < 3; ++c) {
      int i = c * 512 + tid;
      int kj = i / 24, dp = (i - kj * 24) * 4;
      if (dp < split) { ksrc[c] = kb1 + (bTk + kj) * krs1 + dp; kstep[c] = (int)(64 * krs1); }
      else            { ksrc[c] = kb2 + (bTk + kj) * krs2 + (dp - split); kstep[c] = (int)(64 * krs2); }
    }
    const ushort* vsrcA = vb + (bTk + vkjp) * vrs + vd0;
    const ushort* vsrcB = vb + (bTk + vkjp + 1) * vrs + vd0;
    int vstep = (int)(64 * vrs);

    ushort4 kpre0[3], kpre1[3];
    ushort2 vpa0, vpb0, vpa1, vpb1;

    f32x16 of;
#pragma unroll
    for (int r2 = 0; r2 < 16; ++r2) of[r2] = 0.f;
    float lsum = 0.f;

    auto do_tile = [&](int kt, const short* Kss, const short* Vss) {
      int krow0 = kt * 64;
      const short* Qrow = Qsm + (qsub * 32 + l31) * 104 + half * 8;
      // ---- S^T = K · Q^T ----  (Q fragment re-read from LDS per tile)
      f32x16 sfT[2];
#pragma unroll
      for (int r2 = 0; r2 < 16; ++r2) { sfT[0][r2] = 0.f; sfT[1][r2] = 0.f; }
#pragma unroll
      for (int ks = 0; ks < 6; ++ks) {
        bf16x8 qk = *(const bf16x8*)(Qrow + ks * 16);
#pragma unroll
        for (int kb = 0; kb < 2; ++kb) {
          bf16x8 ak = *(const bf16x8*)(Kss + (kb * 32 + l31) * 104 + ks * 16 + half * 8);
          sfT[kb] = __builtin_amdgcn_mfma_f32_32x32x16_bf16(ak, qk, sfT[kb], 0, 0, 0);
        }
      }
      // C-layout: col=lane&31=q_local, row=key_local=(reg&3)+8*(reg>>2)+4*half
      int qg = qrow0 + qsub * 32 + l31;
      int domask = causal && (kt >= 2 * qtile);
      unsigned w01[2][4], w23[2][4];
#pragma unroll
      for (int kb = 0; kb < 2; ++kb) {
#pragma unroll
        for (int gg = 0; gg < 4; ++gg) {
          int key0 = krow0 + kb * 32 + 8 * gg + 4 * half;
          float t0 = sfT[kb][gg * 4 + 0];
          float t1 = sfT[kb][gg * 4 + 1];
          float t2 = sfT[kb][gg * 4 + 2];
          float t3 = sfT[kb][gg * 4 + 3];
          if (domask) {
            if (key0 + 0 > qg) t0 = -INFINITY;
            if (key0 + 1 > qg) t1 = -INFINITY;
            if (key0 + 2 > qg) t2 = -INFINITY;
            if (key0 + 3 > qg) t3 = -INFINITY;
          }
          float p0 = __builtin_amdgcn_exp2f(t0);
          float p1 = __builtin_amdgcn_exp2f(t1);
          float p2 = __builtin_amdgcn_exp2f(t2);
          float p3 = __builtin_amdgcn_exp2f(t3);
          lsum += (p0 + p1) + (p2 + p3);
          asm("v_cvt_pk_bf16_f32 %0, %1, %2" : "=v"(w01[kb][gg]) : "v"(p0), "v"(p1));
          asm("v_cvt_pk_bf16_f32 %0, %1, %2" : "=v"(w23[kb][gg]) : "v"(p2), "v"(p3));
        }
      }
      // ---- O += P · V ----  (permlane32_swap assembles PV A-frag, no LDS trip)
#pragma unroll
      for (int ks2 = 0; ks2 < 4; ++ks2) {
        int kb = ks2 >> 1, gA = 2 * (ks2 & 1);
        unsigned a0 = w01[kb][gA], b0 = w01[kb][gA + 1];
        unsigned a1 = w23[kb][gA], b1 = w23[kb][gA + 1];
        asm("v_permlane32_swap_b32 %0, %1" : "+v"(a0), "+v"(b0));
        asm("v_permlane32_swap_b32 %0, %1" : "+v"(a1), "+v"(b1));
        union { unsigned u[4]; bf16x8 v; } ap;
        ap.u[0] = a0; ap.u[1] = a1; ap.u[2] = b0; ap.u[3] = b1;
        bf16x8 bv = *(const bf16x8*)(Vss + l31 * 72 + ks2 * 16 + half * 8);
        of = __builtin_amdgcn_mfma_f32_32x32x16_bf16(ap.v, bv, of, 0, 0, 0);
      }
    };

    int nkt = causal ? (2 * qtile + 2) : 8;  // always even -> equal parity tiles
    PREFETCH(kpre0, vpa0, vpb0);             // tile 0
    PREFETCH(kpre1, vpa1, vpb1);             // tile 1
    for (int kt = 0; kt < nkt; kt += 2) {
      __syncthreads();  // prior pair's compute done; slots free
      COMMIT(kpre0, vpa0, vpb0, 0);
      COMMIT(kpre1, vpa1, vpb1, 1);
      if (kt + 2 < nkt) PREFETCH(kpre0, vpa0, vpb0);
      if (kt + 3 < nkt) PREFETCH(kpre1, vpa1, vpb1);
      __syncthreads();  // slots ready
      if (khalf == 0) do_tile(kt, Ksm, Vtm);
      else            do_tile(kt + 1, Ksm + 64 * 104, Vtm + 32 * 72);
    }

    // ---- fold parity-1 (of,lsum) into parity-0 via Ksm ----
    lsum += __shfl_xor(lsum, 32, 64);
    __syncthreads();                   // all compute done; Ksm free
    float* red = (float*)Ksm;          // [4][64][17] f32 (stride 17: conflict-free)
    int rbase = (qsub * 64 + lane) * 17;
    if (khalf == 1) {
#pragma unroll
      for (int r2 = 0; r2 < 16; ++r2) red[rbase + r2] = of[r2];
      red[rbase + 16] = lsum;
    }
    __syncthreads();
    if (khalf == 0) {
#pragma unroll
      for (int r2 = 0; r2 < 16; ++r2) of[r2] += red[rbase + r2];
      lsum += red[rbase + 16];
      if (half == 0) Ls[qsub * 32 + l31] = lsum;
    }
    asm volatile("s_waitcnt lgkmcnt(0)" ::: "memory");  // wave-private Ls
    if (khalf == 0) {
      float wgt = (s == 0) ? w0 : ((s == 1) ? w1 : w2);
#pragma unroll
      for (int reg = 0; reg < 16; ++reg) {
        int ql = (reg & 3) + 8 * (reg >> 2) + 4 * half;
        Oac[obase + reg] += of[reg] * (wgt / Ls[qsub * 32 + ql]);
      }
    }
  }
#undef PREFETCH
#undef COMMIT

  // epilogue: parity-0 waves write O (C-layout col=lane&31=dv, row=q_local)
  if (khalf == 0) {
#pragma unroll
    for (int reg = 0; reg < 16; ++reg) {
      int trow = qrow0 + qsub * 32 + (reg & 3) + 8 * (reg >> 2) + 4 * half;
      attout[(size_t)(b * TT + trow) * 512 + h * 32 + l31] = (ushort)f2bf(Oac[obase + reg]);
    }
  }
}

// ---------------- launch ----------------
extern "C" void kernel_launch(void* const* d_in, const int* in_sizes, int n_in,
                              void* d_out, int out_size, void* d_ws, size_t ws_size,
                              hipStream_t stream) {
  const float* x      = (const float*)d_in[0];
  const float* W_cq   = (const float*)d_in[1];
  const float* qnw    = (const float*)d_in[2];
  const float* W_dqn  = (const float*)d_in[3];
  const float* W_dqr  = (const float*)d_in[4];
  const float* W_ckv  = (const float*)d_in[5];
  const float* kvnw   = (const float*)d_in[6];
  const float* W_dkn  = (const float*)d_in[7];
  const float* W_dv   = (const float*)d_in[8];
  const float* W_kr   = (const float*)d_in[9];
  const float* W_imp  = (const float*)d_in[10];
  const float* b_imp  = (const float*)d_in[11];
  const float* W_selk = (const float*)d_in[12];
  const float* W_selv = (const float*)d_in[13];
  const float* W_wink = (const float*)d_in[14];
  const float* W_winv = (const float*)d_in[15];
  const float* W_gate = (const float*)d_in[16];
  const float* b_gate = (const float*)d_in[17];
  const float* W_proj = (const float*)d_in[18];
  const float* cos_f  = (const float*)d_in[19];
  const float* sin_f  = (const float*)d_in[20];
  float* out = (float*)d_out;
  float* ws  = (float*)d_ws;

  size_t off = 0;
  auto alloc = [&](size_t n) {
    float* p = ws + off;
    off += (n + 255) & ~(size_t)255;
    return p;
  };
  const int ROWS = 2 * TT;  // 4096
  ushort* xbf     = (ushort*)alloc((size_t)ROWS * 128);
  ushort* xhb     = (ushort*)alloc((size_t)ROWS * 128);
  ushort* nqb     = (ushort*)alloc((size_t)ROWS * 48);
  ushort* qbf     = (ushort*)alloc((size_t)ROWS * 768);   // [qn 512 | qr 1024] bf16
  ushort* nkvb    = (ushort*)alloc((size_t)ROWS * 16);
  ushort* kvtmp   = (ushort*)alloc((size_t)ROWS * 512);   // [kn 512 | v 512] bf16
  ushort* krbf    = (ushort*)alloc((size_t)ROWS * 32);
  float* scores   = alloc(ROWS);
  float* gacc     = alloc(8);                             // [2][3] gate sums
  int* selidx     = (int*)alloc(1024);
  int* selflags   = (int*)alloc(ROWS);
  ushort* seltmp  = (ushort*)alloc((size_t)1024 * 1024);  // [sk|sv] bf16
  ushort* wintmp  = (ushort*)alloc((size_t)ROWS * 1024);  // [wk|wv] bf16
  ushort* attoutb = (ushort*)alloc((size_t)ROWS * 256);   // [4096][512] bf16
  ushort* Wt_q    = (ushort*)alloc((size_t)1536 * 48);
  ushort* Wt_kv   = (ushort*)alloc((size_t)1024 * 16);
  ushort* Wt_sel  = (ushort*)alloc((size_t)2048 * 128);
  ushort* Wt_win  = (ushort*)alloc((size_t)2048 * 128);
  ushort* Wt_proj = (ushort*)alloc((size_t)256 * 256);
  ushort* Wt_cq   = (ushort*)alloc((size_t)128 * 128);
  ushort* Wt_nkv  = (ushort*)alloc((size_t)128 * 128);

  // 1) logmap + tiled weight transpose + gacc zero (fused)
  prep_kernel<<<4096 + 368, 256, 0, stream>>>(
      x, xhb, xbf,
      W_dqn, W_dqr, W_dkn, W_dv, W_selk, W_selv, W_wink, W_winv, W_proj,
      W_cq, W_ckv, W_kr, W_gate, W_imp,
      Wt_q, Wt_kv, Wt_sel, Wt_win, Wt_proj, Wt_cq, Wt_nkv, gacc);

  // 2) front GEMMs + FUSED NORM (z=0: xh@W_cq -> nqb rmsnorm'd;
  //    z=1: x@W_nkv -> nkvb rmsnorm'd + krbf rope + scores + gate reduce)
  gemm_kernel<<<dim3(32, 1, 2), 256, 0, stream>>>(
      xhb, Wt_cq, nqb, xbf, Wt_nkv, nkvb,
      nullptr, nullptr, nullptr, nullptr, nullptr, nullptr, nullptr,
      cos_f, sin_f, gacc,
      kvnw, qnw, b_imp, krbf, scores, 1,
      256, 96, 1, 0, 256, 32, 1, 0, 32, 1,
      0, 0, 0, 0, 0, 0, 0, 0, 0, 0, 0, 0);

  // 3-4) top-k (needs only scores)
  topk_rank_kernel<<<dim3(64, 2), 1024, 0, stream>>>(scores, selflags);
  topk_scan_kernel<<<2, 1024, 0, stream>>>(selflags, selidx);

  // 5) ALL remaining projections in ONE launch (4-way z):
  //    z0 win (32x16), z1 sel gather (8x16), z2 Q proj + rope (32x12), z3 KV (32x8)
  gemm_kernel<<<dim3(32, 16, 4), 256, 0, stream>>>(
      xbf, Wt_win, wintmp, xbf, Wt_sel, seltmp,
      selidx, nqb, Wt_q, qbf, nkvb, Wt_kv, kvtmp,
      cos_f, sin_f, nullptr,
      nullptr, nullptr, nullptr, nullptr, nullptr, 0,
      256, 2048, 1, 0, 256, 2048, 1, 0, 8, 16,
      96, 1536, 1, 1, 32, 12,
      32, 1024, 1, 0, 32, 8);

  // 6) fused flash attention (gate softmax inline)
  flash_fused_kernel<<<512, 512, 0, stream>>>(qbf, kvtmp, krbf, seltmp, wintmp,
                                              gacc, b_gate, attoutb);

  // 7) output projection
  gemm_kernel<<<dim3(32, 2, 1), 256, 0, stream>>>(
      attoutb, Wt_proj, out, nullptr, nullptr, nullptr,
      nullptr, nullptr, nullptr, nullptr, nullptr, nullptr, nullptr,
      nullptr, nullptr, nullptr,
      nullptr, nullptr, nullptr, nullptr, nullptr, 0,
      512, 256, 0, 0, 0, 0, 0, 0, 0, 0,
      0, 0, 0, 0, 0, 0, 0, 0, 0, 0, 0, 0);
}

// Round 15
// 247.635 us; speedup vs baseline: 1.1605x; 1.1605x over previous
//
#include <hip/hip_runtime.h>
#include <hip/hip_bf16.h>
#include <math.h>

#define TT 2048
#define NE 256
#define NHEAD 16

typedef __attribute__((ext_vector_type(8))) short bf16x8;
typedef __attribute__((ext_vector_type(4))) float f32x4;
typedef __attribute__((ext_vector_type(16))) float f32x16;
typedef unsigned short ushort;
typedef __attribute__((ext_vector_type(8))) unsigned short us8;

__device__ __forceinline__ short f2bf(float x) {
  __hip_bfloat16 h = __float2bfloat16(x);
  return *reinterpret_cast<short*>(&h);
}
__device__ __forceinline__ float bf2f(ushort u) {
  unsigned v = ((unsigned)u) << 16;
  return __uint_as_float(v);
}

// ---------------- fused prep: logmap (blocks 0..4095) + TILED weight transpose ----------------
__global__ __launch_bounds__(256) void prep_kernel(
    const float* __restrict__ x, ushort* __restrict__ xhb, ushort* __restrict__ xbf,
    const float* __restrict__ W_dqn, const float* __restrict__ W_dqr,
    const float* __restrict__ W_dkn, const float* __restrict__ W_dv,
    const float* __restrict__ W_selk, const float* __restrict__ W_selv,
    const float* __restrict__ W_wink, const float* __restrict__ W_winv,
    const float* __restrict__ W_proj, const float* __restrict__ W_cq,
    const float* __restrict__ W_ckv, const float* __restrict__ W_kr,
    const float* __restrict__ W_gate, const float* __restrict__ W_imp,
    ushort* __restrict__ Wt_q, ushort* __restrict__ Wt_kv,
    ushort* __restrict__ Wt_sel, ushort* __restrict__ Wt_win,
    ushort* __restrict__ Wt_proj, ushort* __restrict__ Wt_cq,
    ushort* __restrict__ Wt_nkv, float* __restrict__ gacc) {
  __shared__ float red[16];
  __shared__ float tl[64 * 65];  // transpose tile (+1 pad)
  int bx = blockIdx.x, tid = threadIdx.x;
  if (bx < 4096) {  // ---- logmap ----
    int row = bx;
    int t = row & (TT - 1);
    float uv = x[row * NE + tid];
    float rv = (t == 0) ? 0.f : x[row * NE - NE + tid];
    xbf[row * NE + tid] = (ushort)f2bf(uv);
    float a = rv * rv, bq = uv * uv, c2 = -rv * uv;
#pragma unroll
    for (int off = 32; off > 0; off >>= 1) {
      a += __shfl_down(a, off, 64);
      bq += __shfl_down(bq, off, 64);
      c2 += __shfl_down(c2, off, 64);
    }
    if ((tid & 63) == 0) {
      int w = tid >> 6;
      red[w] = a; red[4 + w] = bq; red[8 + w] = c2;
    }
    __syncthreads();
    float xn2 = red[0] + red[1] + red[2] + red[3];
    float un2 = red[4] + red[5] + red[6] + red[7];
    float ip  = red[8] + red[9] + red[10] + red[11];
    float den = 1.f + 2.f * ip + xn2 * un2;
    float mob = ((1.f + 2.f * ip + un2) * (-rv) + (1.f - xn2) * uv) / den;
    float m2 = mob * mob;
#pragma unroll
    for (int off = 32; off > 0; off >>= 1) m2 += __shfl_down(m2, off, 64);
    if ((tid & 63) == 0) red[12 + (tid >> 6)] = m2;
    __syncthreads();
    float an2 = red[12] + red[13] + red[14] + red[15];
    float an = sqrtf(an2);
    float cf = 1.f + xn2;
    float arg = fminf(sqrtf(an), 0.999f);
    xhb[row * NE + tid] = (ushort)f2bf(cf * atanhf(arg) * mob / an);
    return;
  }
  // ---- tiled weight transpose: 368 tiles total ----
  int tix = bx - 4096;
  if (tix == 0 && tid < 6) gacc[tid] = 0.f;  // zero gate accs (before front gemm)
  int which, tn, tk, N, K;
  ushort* D;
  float scl = 1.f;
  if (tix < 48) {        // Wt_q  [1536 n][96 k], scale folded
    which = 0; tn = tix >> 1; tk = tix & 1; N = 1536; K = 96; D = Wt_q;
    scl = 0.147244458176154f;  // 1/sqrt(96)*log2(e)
  } else if (tix < 64) { // Wt_kv [1024 n][32 k]
    which = 1; tn = tix - 48; tk = 0; N = 1024; K = 32; D = Wt_kv;
  } else if (tix < 192) {  // Wt_sel [2048 n][256 k]
    which = 2; int idx = tix - 64; tn = idx >> 2; tk = idx & 3; N = 2048; K = 256; D = Wt_sel;
  } else if (tix < 320) {  // Wt_win [2048 n][256 k]
    which = 3; int idx = tix - 192; tn = idx >> 2; tk = idx & 3; N = 2048; K = 256; D = Wt_win;
  } else if (tix < 352) {  // Wt_proj [256 n][512 k]
    which = 4; int idx = tix - 320; tn = idx >> 3; tk = idx & 7; N = 256; K = 512; D = Wt_proj;
  } else if (tix < 360) {  // Wt_cq [128 n][256 k] (pad n>=96)
    which = 5; int idx = tix - 352; tn = idx >> 2; tk = idx & 3; N = 128; K = 256; D = Wt_cq;
  } else {                 // Wt_nkv [128 n][256 k]: [ckv32|kr64|gate3|imp1|pad]
    which = 6; int idx = tix - 360; tn = idx >> 2; tk = idx & 3; N = 128; K = 256; D = Wt_nkv;
  }
  int n0 = tn * 64, k0 = tk * 64;
#pragma unroll
  for (int it = 0; it < 16; ++it) {
    int flat = it * 256 + tid;
    int kk = flat >> 6, nn = flat & 63;
    int k = k0 + kk, n = n0 + nn;
    float v = 0.f;
    if (k < K) {
      if (which == 0)      v = ((n < 512) ? W_dqn[(size_t)k * 512 + n]
                                          : W_dqr[(size_t)k * 1024 + (n - 512)]) * scl;
      else if (which == 1) v = (n < 512) ? W_dkn[(size_t)k * 512 + n]
                                         : W_dv[(size_t)k * 512 + (n - 512)];
      else if (which == 2) v = (n < 1536) ? W_selk[(size_t)k * 1536 + n]
                                          : W_selv[(size_t)k * 512 + (n - 1536)];
      else if (which == 3) v = (n < 1536) ? W_wink[(size_t)k * 1536 + n]
                                          : W_winv[(size_t)k * 512 + (n - 1536)];
      else if (which == 4) v = W_proj[(size_t)k * 256 + n];
      else if (which == 5) v = (n < 96) ? W_cq[(size_t)k * 96 + n] : 0.f;
      else {
        if (n < 32)       v = W_ckv[(size_t)k * 32 + n];
        else if (n < 96)  v = W_kr[(size_t)k * 64 + (n - 32)];
        else if (n < 99)  v = W_gate[(size_t)k * 3 + (n - 96)];
        else if (n == 99) v = W_imp[k];
      }
    }
    tl[kk * 65 + nn] = v;
  }
  __syncthreads();
#pragma unroll
  for (int it = 0; it < 4; ++it) {
    int flat = it * 256 + tid;        // 1024 ushort4 slots per tile
    int nl = flat >> 4, k4 = (flat & 15) * 4;
    if (k0 + k4 < K) {
      ushort4 o;
      o.x = (ushort)f2bf(tl[(k4 + 0) * 65 + nl]);
      o.y = (ushort)f2bf(tl[(k4 + 1) * 65 + nl]);
      o.z = (ushort)f2bf(tl[(k4 + 2) * 65 + nl]);
      o.w = (ushort)f2bf(tl[(k4 + 3) * 65 + nl]);
      *(ushort4*)(D + (size_t)(n0 + nl) * K + k0 + k4) = o;
    }
  }
}

// ---------------- bf16 MFMA GEMM: D[m][n] = sum_k A[m][k] * Bt[n][k] ----------------
// 4-way z-dispatch: z selects param set {1,2,3,4}; each set clipped to its
// (xlim,ylim). Set 2 supports selidx gather. ropemode: q-rope in epilogue.
// fusenorm: norm fused into epilogue (R10).
__global__ __launch_bounds__(256) void gemm_kernel(const ushort* __restrict__ A,
                                                   const ushort* __restrict__ Bt,
                                                   void* __restrict__ Out,
                                                   const ushort* __restrict__ A2,
                                                   const ushort* __restrict__ Bt2,
                                                   void* __restrict__ Out2,
                                                   const int* __restrict__ selidx2,
                                                   const ushort* __restrict__ A3,
                                                   const ushort* __restrict__ Bt3,
                                                   void* __restrict__ Out3,
                                                   const ushort* __restrict__ A4,
                                                   const ushort* __restrict__ Bt4,
                                                   void* __restrict__ Out4,
                                                   const float* __restrict__ cosp,
                                                   const float* __restrict__ sinp,
                                                   float* __restrict__ gateacc,
                                                   const float* __restrict__ kvnw,
                                                   const float* __restrict__ qnw,
                                                   const float* __restrict__ bimp,
                                                   ushort* __restrict__ krbf_o,
                                                   float* __restrict__ scores_o,
                                                   int fusenorm,
                                                   int K, int ldo, int obf16, int ropemode,
                                                   int K2, int ldo2, int obf2, int rope2,
                                                   int xlim2, int ylim2,
                                                   int K3, int ldo3, int obf3, int rope3,
                                                   int xlim3, int ylim3,
                                                   int K4, int ldo4, int obf4, int rope4,
                                                   int xlim4, int ylim4) {
  __shared__ __align__(16) short gsm[2 * 128 * 40];  // As | Bs; reused as f32 scratch
  short* As = gsm;
  short* Bs = gsm + 128 * 40;
  const int* selidx = nullptr;
  if (blockIdx.z == 1) {
    if ((int)blockIdx.x >= xlim2 || (int)blockIdx.y >= ylim2) return;
    A = A2; Bt = Bt2; Out = Out2; selidx = selidx2;
    K = K2; ldo = ldo2; obf16 = obf2; ropemode = rope2;
  } else if (blockIdx.z == 2) {
    if ((int)blockIdx.x >= xlim3 || (int)blockIdx.y >= ylim3) return;
    A = A3; Bt = Bt3; Out = Out3;
    K = K3; ldo = ldo3; obf16 = obf3; ropemode = rope3;
  } else if (blockIdx.z == 3) {
    if ((int)blockIdx.x >= xlim4 || (int)blockIdx.y >= ylim4) return;
    A = A4; Bt = Bt4; Out = Out4;
    K = K4; ldo = ldo4; obf16 = obf4; ropemode = rope4;
  }
  int m0 = blockIdx.x * 128, n0 = blockIdx.y * 128;
  int tid = threadIdx.x;
  int wv = tid >> 6, lane = tid & 63;
  int l15 = lane & 15, quad = lane >> 4;
  int wm = wv >> 1, wn = wv & 1;

  int r = tid >> 1, seg = tid & 1;
  int arow = m0 + r;
  if (selidx) arow = ((arow >> 9) * TT) + selidx[m0 + r];
  const ushort* ga = A + (size_t)arow * K + seg * 16;
  const ushort* gb = Bt + (size_t)(n0 + r) * K + seg * 16;

  f32x4 acc[4][4];
#pragma unroll
  for (int i = 0; i < 4; ++i)
#pragma unroll
    for (int j = 0; j < 4; ++j) acc[i][j] = (f32x4){0.f, 0.f, 0.f, 0.f};

  int nk = K >> 5;
  us8 apre0 = *(const us8*)ga, apre1 = *(const us8*)(ga + 8);
  us8 bpre0 = *(const us8*)gb, bpre1 = *(const us8*)(gb + 8);
  for (int kk = 0; kk < nk; ++kk) {
    __syncthreads();
    *(us8*)(As + r * 40 + seg * 16) = apre0;
    *(us8*)(As + r * 40 + seg * 16 + 8) = apre1;
    *(us8*)(Bs + r * 40 + seg * 16) = bpre0;
    *(us8*)(Bs + r * 40 + seg * 16 + 8) = bpre1;
    __syncthreads();
    if (kk + 1 < nk) {
      apre0 = *(const us8*)(ga + (kk + 1) * 32);
      apre1 = *(const us8*)(ga + (kk + 1) * 32 + 8);
      bpre0 = *(const us8*)(gb + (kk + 1) * 32);
      bpre1 = *(const us8*)(gb + (kk + 1) * 32 + 8);
    }
    bf16x8 af[4], bf[4];
#pragma unroll
    for (int mf = 0; mf < 4; ++mf)
      af[mf] = *(const bf16x8*)(As + (wm * 64 + mf * 16 + l15) * 40 + quad * 8);
#pragma unroll
    for (int nf = 0; nf < 4; ++nf)
      bf[nf] = *(const bf16x8*)(Bs + (wn * 64 + nf * 16 + l15) * 40 + quad * 8);
#pragma unroll
    for (int mf = 0; mf < 4; ++mf)
#pragma unroll
      for (int nf = 0; nf < 4; ++nf)
        acc[mf][nf] = __builtin_amdgcn_mfma_f32_16x16x32_bf16(af[mf], bf[nf], acc[mf][nf], 0, 0, 0);
  }

  if (fusenorm) {
    // -------- fused norm epilogue (front gemm; n0==0, full rows in block) --------
    __syncthreads();  // all waves' MFMA LDS reads done; gsm reusable as f32 scratch
    float* sc = (float*)gsm;  // 5120 f32 available
    if (blockIdx.z == 0) {
      // ---- nq rmsnorm over cols 0..95 -> nqb [row][96] bf16 ----
      float ss[4][4];
#pragma unroll
      for (int mf = 0; mf < 4; ++mf)
#pragma unroll
        for (int reg = 0; reg < 4; ++reg) {
          float p = acc[mf][0][reg] * acc[mf][0][reg] + acc[mf][1][reg] * acc[mf][1][reg];
          if (wn == 0) p += acc[mf][2][reg] * acc[mf][2][reg] + acc[mf][3][reg] * acc[mf][3][reg];
#pragma unroll
          for (int off = 8; off > 0; off >>= 1) p += __shfl_xor(p, off, 64);  // reduce l15
          ss[mf][reg] = p;
        }
      if (l15 == 0) {
#pragma unroll
        for (int mf = 0; mf < 4; ++mf)
#pragma unroll
          for (int reg = 0; reg < 4; ++reg)
            sc[wn * 128 + wm * 64 + mf * 16 + quad * 4 + reg] = ss[mf][reg];
      }
      __syncthreads();
#pragma unroll
      for (int mf = 0; mf < 4; ++mf) {
#pragma unroll
        for (int nf = 0; nf < 4; ++nf) {
          if (wn == 1 && nf >= 2) continue;  // cols >= 96 are pad
          int col = wn * 64 + nf * 16 + l15;
#pragma unroll
          for (int reg = 0; reg < 4; ++reg) {
            int rl = wm * 64 + mf * 16 + quad * 4 + reg;
            float sstot = sc[rl] + sc[128 + rl];
            float sca = rsqrtf(sstot / 96.f + 1e-6f) * qnw[col];
            ((ushort*)Out)[(size_t)(m0 + rl) * 96 + col] = (ushort)f2bf(acc[mf][nf][reg] * sca);
          }
        }
      }
    } else {
      // ---- gate reduce: cols 96..98 (wn==1, nf==2, l15<3) ----
      if (wn == 1 && l15 < 3) {
        float g = 0.f;
#pragma unroll
        for (int mf = 0; mf < 4; ++mf)
#pragma unroll
          for (int reg = 0; reg < 4; ++reg) g += acc[mf][2][reg];
        atomicAdd(&gateacc[(m0 >> 11) * 3 + l15], g);
      }
      // ---- scores = col 99 + b_imp (wn==1, nf==2, l15==3) ----
      if (wn == 1 && l15 == 3) {
#pragma unroll
        for (int mf = 0; mf < 4; ++mf)
#pragma unroll
          for (int reg = 0; reg < 4; ++reg)
            scores_o[m0 + wm * 64 + mf * 16 + quad * 4 + reg] = acc[mf][2][reg] + bimp[0];
      }
      // ---- kv rmsnorm cols 0..31 (wn==0; in-wave l15 reduce) -> nkvb ----
      if (wn == 0) {
#pragma unroll
        for (int mf = 0; mf < 4; ++mf) {
          float ssr[4];
#pragma unroll
          for (int reg = 0; reg < 4; ++reg) {
            float p = acc[mf][0][reg] * acc[mf][0][reg] + acc[mf][1][reg] * acc[mf][1][reg];
#pragma unroll
            for (int off = 8; off > 0; off >>= 1) p += __shfl_xor(p, off, 64);
            ssr[reg] = p;
          }
#pragma unroll
          for (int nf = 0; nf < 2; ++nf) {
            int col = nf * 16 + l15;
#pragma unroll
            for (int reg = 0; reg < 4; ++reg) {
              int rl = wm * 64 + mf * 16 + quad * 4 + reg;
              float sca = rsqrtf(ssr[reg] / 32.f + 1e-6f) * kvnw[col];
              ((ushort*)Out)[(size_t)(m0 + rl) * 32 + col] = (ushort)f2bf(acc[mf][nf][reg] * sca);
            }
          }
        }
      }
      // ---- xi exchange: wn==1 writes cols 64..95 to sc[rl*33+dd] ----
      if (wn == 1) {
#pragma unroll
        for (int mf = 0; mf < 4; ++mf)
#pragma unroll
          for (int nf = 0; nf < 2; ++nf) {
            int dd = nf * 16 + l15;
#pragma unroll
            for (int reg = 0; reg < 4; ++reg) {
              int rl = wm * 64 + mf * 16 + quad * 4 + reg;
              sc[rl * 33 + dd] = acc[mf][nf][reg];
            }
          }
      }
      __syncthreads();
      // ---- kr rope: wn==0, nf=2,3 hold xr cols 32..63; xi from LDS -> krbf ----
      if (wn == 0) {
#pragma unroll
        for (int mf = 0; mf < 4; ++mf)
#pragma unroll
          for (int nf = 2; nf < 4; ++nf) {
            int dd = (nf - 2) * 16 + l15;
#pragma unroll
            for (int reg = 0; reg < 4; ++reg) {
              int rl = wm * 64 + mf * 16 + quad * 4 + reg;
              int grow = m0 + rl;
              int t = grow & (TT - 1);
              float c = cosp[t * 32 + dd], s = sinp[t * 32 + dd];
              float xr = acc[mf][nf][reg], xi = sc[rl * 33 + dd];
              krbf_o[(size_t)grow * 64 + dd] = (ushort)f2bf(xr * c - xi * s);
              krbf_o[(size_t)grow * 64 + dd + 32] = (ushort)f2bf(xr * s + xi * c);
            }
          }
      }
    }
    return;
  }

  if (ropemode && blockIdx.y >= 4) {
    // rope pairs: cols (c, c+32) live in frags (nf, nf+2), nf in {0,1}
#pragma unroll
    for (int mf = 0; mf < 4; ++mf) {
#pragma unroll
      for (int nf = 0; nf < 2; ++nf) {
        int dd = nf * 16 + l15;
#pragma unroll
        for (int reg = 0; reg < 4; ++reg) {
          int row = m0 + wm * 64 + mf * 16 + quad * 4 + reg;
          int t = row & (TT - 1);
          float c = cosp[t * 32 + dd], s = sinp[t * 32 + dd];
          float xr = acc[mf][nf][reg], xi = acc[mf][nf + 2][reg];
          int col = n0 + wn * 64 + nf * 16 + l15;
          size_t oi = (size_t)row * ldo + col;
          ((ushort*)Out)[oi] = (ushort)f2bf(xr * c - xi * s);
          ((ushort*)Out)[oi + 32] = (ushort)f2bf(xr * s + xi * c);
        }
      }
    }
    return;
  }
#pragma unroll
  for (int mf = 0; mf < 4; ++mf) {
#pragma unroll
    for (int nf = 0; nf < 4; ++nf) {
#pragma unroll
      for (int reg = 0; reg < 4; ++reg) {
        int row = m0 + wm * 64 + mf * 16 + quad * 4 + reg;
        int col = n0 + wn * 64 + nf * 16 + l15;
        size_t oi = (size_t)row * ldo + col;
        float v = acc[mf][nf][reg];
        if (obf16) ((ushort*)Out)[oi] = (ushort)f2bf(v);
        else ((float*)Out)[oi] = v;
      }
    }
  }
}

// ---------------- top-k stage 1: ranks -> flags (32 elems x 32 subs / block) ----------------
__global__ __launch_bounds__(1024) void topk_rank_kernel(const float* __restrict__ scores,
                                                         int* __restrict__ flags) {
  int b = blockIdx.y, blk = blockIdx.x;  // blk in 0..63
  int tid = threadIdx.x;
  __shared__ unsigned sk[TT];
#pragma unroll
  for (int e = 0; e < 2; ++e) {
    int i = tid + e * 1024;
    float s = scores[b * TT + i];
    unsigned u = __float_as_uint(s);
    u = (u & 0x80000000u) ? ~u : (u | 0x80000000u);
    sk[i] = u;
  }
  __syncthreads();
  int e = blk * 32 + (tid >> 5);
  int sub = tid & 31;
  unsigned u = sk[e];
  int r = 0;
  int j0 = sub * 64;
#pragma unroll 8
  for (int j = j0; j < j0 + 64; ++j) {
    unsigned v = sk[j];
    r += (int)((v > u) || (v == u && j < e));
  }
#pragma unroll
  for (int off = 16; off > 0; off >>= 1) r += __shfl_down(r, off, 32);
  if (sub == 0) flags[b * TT + e] = (r < 512) ? 1 : 0;
}

// ---------------- top-k stage 2: wave-shfl scan + scatter (2 barriers) ----------------
__global__ __launch_bounds__(1024) void topk_scan_kernel(const int* __restrict__ flags,
                                                         int* __restrict__ selidx) {
  int b = blockIdx.x, tid = threadIdx.x;
  __shared__ int wsum[16];
  int2 f = *(const int2*)(flags + b * TT + 2 * tid);  // elements 2*tid, 2*tid+1
  int local = f.x + f.y;
  int lane = tid & 63, wv = tid >> 6;
  int sc = local;  // inclusive wave scan
#pragma unroll
  for (int off = 1; off < 64; off <<= 1) {
    int t = __shfl_up(sc, off, 64);
    if (lane >= off) sc += t;
  }
  if (lane == 63) wsum[wv] = sc;
  __syncthreads();
  int woff = 0;
  for (int w = 0; w < wv; ++w) woff += wsum[w];  // broadcast LDS reads
  int p0 = woff + (sc - local) + f.x;  // inclusive prefix at element 2*tid
  int p1 = p0 + f.y;
  if (f.x) selidx[b * 512 + p0 - 1] = 2 * tid;
  if (f.y) selidx[b * 512 + p1 - 1] = 2 * tid + 1;
}

// ---------------- fused flash attention, 32x32x16 MFMA, S^T formulation ----------------
// Phase-locked schedule (R2/R6): 512 blocks, streams cmp->sel->win SEQUENTIAL.
// 512 threads = 8 waves = 4 q-subtiles x 2 TILE-PARITIES; Q + oacc in LDS.
// __launch_bounds__(512, 4): REVERTED from R14's (512,2), which unexpectedly
// halved runtime occupancy (29->16.7%, 1 block/CU, FETCH 34->63 MB, 86->132us)
// despite removing the last ~1 MB of spill. Measured best config: (512,4) =
// VGPR 64 + ~1 MB benign spill + 2 blocks/CU + 86.5 us (R13).
__global__ __launch_bounds__(512, 4) void flash_fused_kernel(
    const ushort* __restrict__ qbf,    // [row][qn 512 | qr 1024] bf16, scale*log2e folded
    const ushort* __restrict__ kv,     // [row][kn 512 | v 512] bf16
    const ushort* __restrict__ krbf,   // [row][64] bf16 (roped)
    const ushort* __restrict__ selt,   // [selrow][sk 1536 | sv 512] bf16
    const ushort* __restrict__ wint,   // [row][wk 1536 | wv 512] bf16
    const float* __restrict__ gacc,    // [2][3] gate sums (from front gemm)
    const float* __restrict__ b_gate,
    ushort* __restrict__ attout) {     // [b*TT+t][h*32+d] bf16
  // shorts: Qsm 13312 | Ksm 13312 | Vtm 4608 | Ls 256 | Oacc 8704  = 40192 (80384 B)
  __shared__ __align__(16) short smem[13312 + 13312 + 4608 + 256 + 8704];
  short* Qsm = smem;                    // [128][104]
  short* Ksm = smem + 13312;            // [2][64*104]
  short* Vtm = smem + 26624;            // [2][32*72]
  float* Ls  = (float*)(smem + 31232);  // [4][32]
  float* Oac = (float*)(smem + 31488);  // [256][17] f32 (stride 17: conflict-free)

  int bx = blockIdx.x;
  int j = bx >> 5;  // 0..15
  int qtile = (j < 8) ? (15 - 2 * j) : (2 * (j - 8));
  int bh = bx & 31;
  int b = bh >> 4, h = bh & 15;
  int tid = threadIdx.x;
  int wv = tid >> 6;          // 0..7
  int qsub = wv >> 1;         // 0..3: q rows qsub*32..+31
  int khalf = wv & 1;         // tile parity
  int lane = tid & 63;
  int l31 = lane & 31, half = lane >> 5;
  int obase = (qsub * 64 + lane) * 17;  // this thread's Oac slot (khalf==0 only)

  // ---- gate softmax (uniform; 3 exp per thread) ----
  float w0, w1, w2;
  {
    float g0 = gacc[b * 3 + 0] * (1.0f / 2048.0f) + b_gate[0];
    float g1 = gacc[b * 3 + 1] * (1.0f / 2048.0f) + b_gate[1];
    float g2 = gacc[b * 3 + 2] * (1.0f / 2048.0f) + b_gate[2];
    float mx = fmaxf(g0, fmaxf(g1, g2));
    float e0 = expf(g0 - mx), e1 = expf(g1 - mx), e2 = expf(g2 - mx);
    float inv = 1.f / (e0 + e1 + e2);
    w0 = e0 * inv; w1 = e1 * inv; w2 = e2 * inv;
  }

  // ---- init Oac (self-owned slots, no barrier needed) ----
  if (khalf == 0) {
#pragma unroll
    for (int r2 = 0; r2 < 16; ++r2) Oac[obase + r2] = 0.f;
  }

  // ---- stage Q into dedicated Qsm (persistent; fragment re-read per tile) ----
  int qrow0 = qtile * 128;
  for (int i = tid; i < 128 * 24; i += 512) {
    int qi = i / 24, dp = (i - qi * 24) * 4;
    int col = (dp < 32) ? (h * 32 + dp) : (512 + h * 64 + (dp - 32));
    *(ushort4*)(Qsm + qi * 104 + dp) =
        *(const ushort4*)(qbf + (size_t)(b * TT + qrow0 + qi) * 1536 + col);
  }
  // K-loop's first __syncthreads orders Qsm staging before first reads

  short* kdst[3];
#pragma unroll
  for (int c = 0; c < 3; ++c) {
    int i = c * 512 + tid;
    int kj = i / 24, dp = (i - kj * 24) * 4;
    kdst[c] = &Ksm[kj * 104 + dp];
  }
  int vd0 = (tid & 15) * 2, vkjp = (tid >> 4) * 2;
  short* vdsta = &Vtm[(vd0 + 0) * 72 + vkjp];
  short* vdstb = &Vtm[(vd0 + 1) * 72 + vkjp];

#define PREFETCH(KP, VA, VB)                                  \
  {                                                           \
    _Pragma("unroll") for (int c = 0; c < 3; ++c) {           \
      KP[c] = *(const ushort4*)ksrc[c];                       \
      ksrc[c] += kstep[c];                                    \
    }                                                         \
    VA = *(const ushort2*)vsrcA;                              \
    VB = *(const ushort2*)vsrcB;                              \
    vsrcA += vstep;                                           \
    vsrcB += vstep;                                           \
  }

#define COMMIT(KP, VA, VB, SL)                                           \
  {                                                                      \
    _Pragma("unroll") for (int c = 0; c < 3; ++c)                        \
      *(ushort4*)(kdst[c] + (SL) * (64 * 104)) = KP[c];                  \
    *(unsigned*)(vdsta + (SL) * (32 * 72)) =                             \
        (unsigned)VA.x | ((unsigned)VB.x << 16);                         \
    *(unsigned*)(vdstb + (SL) * (32 * 72)) =                             \
        (unsigned)VA.y | ((unsigned)VB.y << 16);                         \
  }

  for (int s = 0; s < 3; ++s) {
    const ushort *kb1, *kb2, *vb;
    size_t krs1, krs2, vrs;
    int split, Tk, causal;
    if (s == 0) {  // cmp
      kb1 = kv + h * 32;        krs1 = 1024; split = 32;
      kb2 = krbf;               krs2 = 64;
      vb = kv + 512 + h * 32;   vrs = 1024;
      Tk = TT; causal = 1;
    } else if (s == 1) {  // sel
      kb1 = selt + h * 96;      krs1 = 2048; split = 96;
      kb2 = selt;               krs2 = 2048;
      vb = selt + 1536 + h * 32; vrs = 2048;
      Tk = 512; causal = 0;
    } else {  // win
      kb1 = wint + h * 96;      krs1 = 2048; split = 96;
      kb2 = wint;               krs2 = 2048;
      vb = wint + 1536 + h * 32; vrs = 2048;
      Tk = TT; causal = 1;
    }
    size_t bTk = (size_t)b * Tk;

    const ushort* ksrc[3];
    int kstep[3];
#pragma unroll
    for (int c = 0; c < 3; ++c) {
      int i = c * 512 + tid;
      int kj = i / 24, dp = (i - kj * 24) * 4;
      if (dp < split) { ksrc[c] = kb1 + (bTk + kj) * krs1 + dp; kstep[c] = (int)(64 * krs1); }
      else            { ksrc[c] = kb2 + (bTk + kj) * krs2 + (dp - split); kstep[c] = (int)(64 * krs2); }
    }
    const ushort* vsrcA = vb + (bTk + vkjp) * vrs + vd0;
    const ushort* vsrcB = vb + (bTk + vkjp + 1) * vrs + vd0;
    int vstep = (int)(64 * vrs);

    ushort4 kpre0[3], kpre1[3];
    ushort2 vpa0, vpb0, vpa1, vpb1;

    f32x16 of;
#pragma unroll
    for (int r2 = 0; r2 < 16; ++r2) of[r2] = 0.f;
    float lsum = 0.f;

    auto do_tile = [&](int kt, const short* Kss, const short* Vss) {
      int krow0 = kt * 64;
      const short* Qrow = Qsm + (qsub * 32 + l31) * 104 + half * 8;
      // ---- S^T = K · Q^T ----  (Q fragment re-read from LDS per tile)
      f32x16 sfT[2];
#pragma unroll
      for (int r2 = 0; r2 < 16; ++r2) { sfT[0][r2] = 0.f; sfT[1][r2] = 0.f; }
#pragma unroll
      for (int ks = 0; ks < 6; ++ks) {
        bf16x8 qk = *(const bf16x8*)(Qrow + ks * 16);
#pragma unroll
        for (int kb = 0; kb < 2; ++kb) {
          bf16x8 ak = *(const bf16x8*)(Kss + (kb * 32 + l31) * 104 + ks * 16 + half * 8);
          sfT[kb] = __builtin_amdgcn_mfma_f32_32x32x16_bf16(ak, qk, sfT[kb], 0, 0, 0);
        }
      }
      // C-layout: col=lane&31=q_local, row=key_local=(reg&3)+8*(reg>>2)+4*half
      int qg = qrow0 + qsub * 32 + l31;
      int domask = causal && (kt >= 2 * qtile);
      unsigned w01[2][4], w23[2][4];
#pragma unroll
      for (int kb = 0; kb < 2; ++kb) {
#pragma unroll
        for (int gg = 0; gg < 4; ++gg) {
          int key0 = krow0 + kb * 32 + 8 * gg + 4 * half;
          float t0 = sfT[kb][gg * 4 + 0];
          float t1 = sfT[kb][gg * 4 + 1];
          float t2 = sfT[kb][gg * 4 + 2];
          float t3 = sfT[kb][gg * 4 + 3];
          if (domask) {
            if (key0 + 0 > qg) t0 = -INFINITY;
            if (key0 + 1 > qg) t1 = -INFINITY;
            if (key0 + 2 > qg) t2 = -INFINITY;
            if (key0 + 3 > qg) t3 = -INFINITY;
          }
          float p0 = __builtin_amdgcn_exp2f(t0);
          float p1 = __builtin_amdgcn_exp2f(t1);
          float p2 = __builtin_amdgcn_exp2f(t2);
          float p3 = __builtin_amdgcn_exp2f(t3);
          lsum += (p0 + p1) + (p2 + p3);
          asm("v_cvt_pk_bf16_f32 %0, %1, %2" : "=v"(w01[kb][gg]) : "v"(p0), "v"(p1));
          asm("v_cvt_pk_bf16_f32 %0, %1, %2" : "=v"(w23[kb][gg]) : "v"(p2), "v"(p3));
        }
      }
      // ---- O += P · V ----  (permlane32_swap assembles PV A-frag, no LDS trip)
#pragma unroll
      for (int ks2 = 0; ks2 < 4; ++ks2) {
        int kb = ks2 >> 1, gA = 2 * (ks2 & 1);
        unsigned a0 = w01[kb][gA], b0 = w01[kb][gA + 1];
        unsigned a1 = w23[kb][gA], b1 = w23[kb][gA + 1];
        asm("v_permlane32_swap_b32 %0, %1" : "+v"(a0), "+v"(b0));
        asm("v_permlane32_swap_b32 %0, %1" : "+v"(a1), "+v"(b1));
        union { unsigned u[4]; bf16x8 v; } ap;
        ap.u[0] = a0; ap.u[1] = a1; ap.u[2] = b0; ap.u[3] = b1;
        bf16x8 bv = *(const bf16x8*)(Vss + l31 * 72 + ks2 * 16 + half * 8);
        of = __builtin_amdgcn_mfma_f32_32x32x16_bf16(ap.v, bv, of, 0, 0, 0);
      }
    };

    int nkt = causal ? (2 * qtile + 2) : 8;  // always even -> equal parity tiles
    PREFETCH(kpre0, vpa0, vpb0);             // tile 0
    PREFETCH(kpre1, vpa1, vpb1);             // tile 1
    for (int kt = 0; kt < nkt; kt += 2) {
      __syncthreads();  // prior pair's compute done; slots free
      COMMIT(kpre0, vpa0, vpb0, 0);
      COMMIT(kpre1, vpa1, vpb1, 1);
      if (kt + 2 < nkt) PREFETCH(kpre0, vpa0, vpb0);
      if (kt + 3 < nkt) PREFETCH(kpre1, vpa1, vpb1);
      __syncthreads();  // slots ready
      if (khalf == 0) do_tile(kt, Ksm, Vtm);
      else            do_tile(kt + 1, Ksm + 64 * 104, Vtm + 32 * 72);
    }

    // ---- fold parity-1 (of,lsum) into parity-0 via Ksm ----
    lsum += __shfl_xor(lsum, 32, 64);
    __syncthreads();                   // all compute done; Ksm free
    float* red = (float*)Ksm;          // [4][64][17] f32 (stride 17: conflict-free)
    int rbase = (qsub * 64 + lane) * 17;
    if (khalf == 1) {
#pragma unroll
      for (int r2 = 0; r2 < 16; ++r2) red[rbase + r2] = of[r2];
      red[rbase + 16] = lsum;
    }
    __syncthreads();
    if (khalf == 0) {
#pragma unroll
      for (int r2 = 0; r2 < 16; ++r2) of[r2] += red[rbase + r2];
      lsum += red[rbase + 16];
      if (half == 0) Ls[qsub * 32 + l31] = lsum;
    }
    asm volatile("s_waitcnt lgkmcnt(0)" ::: "memory");  // wave-private Ls
    if (khalf == 0) {
      float wgt = (s == 0) ? w0 : ((s == 1) ? w1 : w2);
#pragma unroll
      for (int reg = 0; reg < 16; ++reg) {
        int ql = (reg & 3) + 8 * (reg >> 2) + 4 * half;
        Oac[obase + reg] += of[reg] * (wgt / Ls[qsub * 32 + ql]);
      }
    }
  }
#undef PREFETCH
#undef COMMIT

  // epilogue: parity-0 waves write O (C-layout col=lane&31=dv, row=q_local)
  if (khalf == 0) {
#pragma unroll
    for (int reg = 0; reg < 16; ++reg) {
      int trow = qrow0 + qsub * 32 + (reg & 3) + 8 * (reg >> 2) + 4 * half;
      attout[(size_t)(b * TT + trow) * 512 + h * 32 + l31] = (ushort)f2bf(Oac[obase + reg]);
    }
  }
}

// ---------------- launch ----------------
extern "C" void kernel_launch(void* const* d_in, const int* in_sizes, int n_in,
                              void* d_out, int out_size, void* d_ws, size_t ws_size,
                              hipStream_t stream) {
  const float* x      = (const float*)d_in[0];
  const float* W_cq   = (const float*)d_in[1];
  const float* qnw    = (const float*)d_in[2];
  const float* W_dqn  = (const float*)d_in[3];
  const float* W_dqr  = (const float*)d_in[4];
  const float* W_ckv  = (const float*)d_in[5];
  const float* kvnw   = (const float*)d_in[6];
  const float* W_dkn  = (const float*)d_in[7];
  const float* W_dv   = (const float*)d_in[8];
  const float* W_kr   = (const float*)d_in[9];
  const float* W_imp  = (const float*)d_in[10];
  const float* b_imp  = (const float*)d_in[11];
  const float* W_selk = (const float*)d_in[12];
  const float* W_selv = (const float*)d_in[13];
  const float* W_wink = (const float*)d_in[14];
  const float* W_winv = (const float*)d_in[15];
  const float* W_gate = (const float*)d_in[16];
  const float* b_gate = (const float*)d_in[17];
  const float* W_proj = (const float*)d_in[18];
  const float* cos_f  = (const float*)d_in[19];
  const float* sin_f  = (const float*)d_in[20];
  float* out = (float*)d_out;
  float* ws  = (float*)d_ws;

  size_t off = 0;
  auto alloc = [&](size_t n) {
    float* p = ws + off;
    off += (n + 255) & ~(size_t)255;
    return p;
  };
  const int ROWS = 2 * TT;  // 4096
  ushort* xbf     = (ushort*)alloc((size_t)ROWS * 128);
  ushort* xhb     = (ushort*)alloc((size_t)ROWS * 128);
  ushort* nqb     = (ushort*)alloc((size_t)ROWS * 48);
  ushort* qbf     = (ushort*)alloc((size_t)ROWS * 768);   // [qn 512 | qr 1024] bf16
  ushort* nkvb    = (ushort*)alloc((size_t)ROWS * 16);
  ushort* kvtmp   = (ushort*)alloc((size_t)ROWS * 512);   // [kn 512 | v 512] bf16
  ushort* krbf    = (ushort*)alloc((size_t)ROWS * 32);
  float* scores   = alloc(ROWS);
  float* gacc     = alloc(8);                             // [2][3] gate sums
  int* selidx     = (int*)alloc(1024);
  int* selflags   = (int*)alloc(ROWS);
  ushort* seltmp  = (ushort*)alloc((size_t)1024 * 1024);  // [sk|sv] bf16
  ushort* wintmp  = (ushort*)alloc((size_t)ROWS * 1024);  // [wk|wv] bf16
  ushort* attoutb = (ushort*)alloc((size_t)ROWS * 256);   // [4096][512] bf16
  ushort* Wt_q    = (ushort*)alloc((size_t)1536 * 48);
  ushort* Wt_kv   = (ushort*)alloc((size_t)1024 * 16);
  ushort* Wt_sel  = (ushort*)alloc((size_t)2048 * 128);
  ushort* Wt_win  = (ushort*)alloc((size_t)2048 * 128);
  ushort* Wt_proj = (ushort*)alloc((size_t)256 * 256);
  ushort* Wt_cq   = (ushort*)alloc((size_t)128 * 128);
  ushort* Wt_nkv  = (ushort*)alloc((size_t)128 * 128);

  // 1) logmap + tiled weight transpose + gacc zero (fused)
  prep_kernel<<<4096 + 368, 256, 0, stream>>>(
      x, xhb, xbf,
      W_dqn, W_dqr, W_dkn, W_dv, W_selk, W_selv, W_wink, W_winv, W_proj,
      W_cq, W_ckv, W_kr, W_gate, W_imp,
      Wt_q, Wt_kv, Wt_sel, Wt_win, Wt_proj, Wt_cq, Wt_nkv, gacc);

  // 2) front GEMMs + FUSED NORM (z=0: xh@W_cq -> nqb rmsnorm'd;
  //    z=1: x@W_nkv -> nkvb rmsnorm'd + krbf rope + scores + gate reduce)
  gemm_kernel<<<dim3(32, 1, 2), 256, 0, stream>>>(
      xhb, Wt_cq, nqb, xbf, Wt_nkv, nkvb,
      nullptr, nullptr, nullptr, nullptr, nullptr, nullptr, nullptr,
      cos_f, sin_f, gacc,
      kvnw, qnw, b_imp, krbf, scores, 1,
      256, 96, 1, 0, 256, 32, 1, 0, 32, 1,
      0, 0, 0, 0, 0, 0, 0, 0, 0, 0, 0, 0);

  // 3-4) top-k (needs only scores)
  topk_rank_kernel<<<dim3(64, 2), 1024, 0, stream>>>(scores, selflags);
  topk_scan_kernel<<<2, 1024, 0, stream>>>(selflags, selidx);

  // 5) ALL remaining projections in ONE launch (4-way z):
  //    z0 win (32x16), z1 sel gather (8x16), z2 Q proj + rope (32x12), z3 KV (32x8)
  gemm_kernel<<<dim3(32, 16, 4), 256, 0, stream>>>(
      xbf, Wt_win, wintmp, xbf, Wt_sel, seltmp,
      selidx, nqb, Wt_q, qbf, nkvb, Wt_kv, kvtmp,
      cos_f, sin_f, nullptr,
      nullptr, nullptr, nullptr, nullptr, nullptr, 0,
      256, 2048, 1, 0, 256, 2048, 1, 0, 8, 16,
      96, 1536, 1, 1, 32, 12,
      32, 1024, 1, 0, 32, 8);

  // 6) fused flash attention (gate softmax inline)
  flash_fused_kernel<<<512, 512, 0, stream>>>(qbf, kvtmp, krbf, seltmp, wintmp,
                                              gacc, b_gate, attoutb);

  // 7) output projection
  gemm_kernel<<<dim3(32, 2, 1), 256, 0, stream>>>(
      attoutb, Wt_proj, out, nullptr, nullptr, nullptr,
      nullptr, nullptr, nullptr, nullptr, nullptr, nullptr, nullptr,
      nullptr, nullptr, nullptr,
      nullptr, nullptr, nullptr, nullptr, nullptr, 0,
      512, 256, 0, 0, 0, 0, 0, 0, 0, 0,
      0, 0, 0, 0, 0, 0, 0, 0, 0, 0, 0, 0);
}